// Round 1
// baseline (776.456 us; speedup 1.0000x reference)
//
#include <hip/hip_runtime.h>

// DeepKoopmanNoDec — fp32 in/out. R4: encoder_tgt restructured around an
// h-in-LDS buffer (64KB, XOR-swizzled) + 4x4 register blocking: weights now
// stream GLOBAL->VGPR (L2-resident, cols wave-partitioned so each B-frag is
// read exactly once per block) — no LDS staging, no per-chunk barriers, LDS
// read volume -75% (was the bound: MfmaUtil 23.7%, HBM 4%). scan_kernel: A
// column held in 128 VGPRs across all 64 steps (was 32KB/wave/step LDS
// re-read); u staged in LDS; f32x4 partial accumulators break dep chains.
// Shapes: B=2048, M=64, STATE=32, EMBED=96, LATENT=128, HIDDEN=512.

typedef unsigned short u16;
typedef __attribute__((ext_vector_type(8))) short bf16x8;   // MFMA A/B frag (4 VGPRs)
typedef __attribute__((ext_vector_type(4))) float f32x4;    // MFMA C/D frag

// ws layout: bf16 B-frag weights, then fp32 z_k
#define OFF_W1 0              // 32 frags   (K=32 , N=512)
#define OFF_W2 16384          // 512 frags  (K=512, N=512)
#define OFF_W3 278528         // 512 frags
#define OFF_WO 540672         // 96 frags   (K=512, N=96)
#define OFF_ZK_BYTES 1179648  // fp32 z_k: 2048*128 floats

// d_out regions (float elements): z_pred | x_pred | z_target
#define XPRED_OFF 16777216
#define ZTGT_OFF  20971520

__device__ __forceinline__ float bf2f(u16 u) {
  unsigned int i = ((unsigned int)u) << 16;
  return __builtin_bit_cast(float, i);
}
__device__ __forceinline__ u16 f2bf(float f) {   // round-to-nearest-even
  unsigned int i = __builtin_bit_cast(unsigned int, f);
  i = (i + 0x7FFFu + ((i >> 16) & 1u)) >> 16;
  return (u16)i;
}

// ---------------------------------------------------------------------------
// Prep: swizzle fp32 weights (row-major K x N) into bf16 B-fragment-linear
// layout. frag f = ct*(K/32)+ks; lane l holds W[ks*32+(l>>4)*8+j][ct*16+(l&15)]
// at u16 offset f*512 + l*8 -> one dwordx4 per lane. (unchanged from R3)
// ---------------------------------------------------------------------------
__global__ void prep_swizzle(const float* __restrict__ W1, const float* __restrict__ W2,
                             const float* __restrict__ W3, const float* __restrict__ Wo,
                             u16* __restrict__ dst) {
  int f = blockIdx.x;
  int l = threadIdx.x;
  const float* src; int K, N; u16* d;
  if (f < 32)        { src = W1; K = 32;  N = 512; d = dst + OFF_W1; }
  else if (f < 544)  { src = W2; K = 512; N = 512; d = dst + OFF_W2; f -= 32; }
  else if (f < 1056) { src = W3; K = 512; N = 512; d = dst + OFF_W3; f -= 544; }
  else               { src = Wo; K = 512; N = 96;  d = dst + OFF_WO; f -= 1056; }
  const int KF = K >> 5;
  const int ct = f / KF, ks = f - ct * KF;
  const int q = l >> 4, n = l & 15;
  const int kbase = ks * 32 + q * 8;
  const int col = ct * 16 + n;
  bf16x8 vh;
  #pragma unroll
  for (int j = 0; j < 8; ++j)
    vh[j] = (short)f2bf(src[(size_t)(kbase + j) * N + col]);
  *(bf16x8*)(d + ((size_t)f * 64 + l) * 8) = vh;
}

// ---------------------------------------------------------------------------
// encoder_tgt helpers. hbuf layout: row-major [64][512] bf16 with per-row XOR
// swizzle on u16 index: idx = (row*512 + k) ^ ((row&7)<<3). XOR bits sit in
// idx bits 3-5, so 8-aligned b128 reads stay contiguous and the 16 lanes of
// an A-frag (row stride 1024B -> all same bank unswizzled) spread over 8
// distinct 16B slots (2-way aliasing = free).
// ---------------------------------------------------------------------------
__device__ __forceinline__ void store_h(const f32x4 (&acc)[4][8],
                                        const float* __restrict__ bias,
                                        u16* hbuf, int wv, int q, int n) {
  __syncthreads();                       // all readers of previous h done
  #pragma unroll
  for (int i = 0; i < 8; ++i) {
    const int col = wv * 128 + i * 16 + n;
    const float bia = bias[col];
    #pragma unroll
    for (int rg = 0; rg < 4; ++rg) {
      #pragma unroll
      for (int r = 0; r < 4; ++r) {
        const int row = rg * 16 + q * 4 + r;    // C layout: col=lane&15, row=(lane>>4)*4+r
        hbuf[(row * 512 + col) ^ ((row & 7) << 3)] = f2bf(fmaxf(acc[rg][i][r] + bia, 0.f));
      }
    }
  }
  __syncthreads();                       // new h visible to all waves
}

// One HIDDEN->HIDDEN layer: 64 rows (all 4 rowgroups) x 8 col-tiles per wave.
// Per ks-chunk: 4 LDS A-frags + 8 global B-frags feed 32 MFMAs (4x reuse on
// both sides). No barriers inside the K loop -> compiler free to pipeline
// the L2 B-loads under MFMA.
__device__ __forceinline__ void big_layer(const u16* __restrict__ wb,
                                          const float* __restrict__ bias,
                                          u16* hbuf, int wv, int l, int q, int n) {
  f32x4 acc[4][8];
  #pragma unroll
  for (int rg = 0; rg < 4; ++rg)
    #pragma unroll
    for (int i = 0; i < 8; ++i) acc[rg][i] = (f32x4){0.f, 0.f, 0.f, 0.f};
  #pragma unroll 4
  for (int ks = 0; ks < 16; ++ks) {
    bf16x8 a[4], b[8];
    #pragma unroll
    for (int rg = 0; rg < 4; ++rg) {
      const int row = rg * 16 + n;       // A layout: row=lane&15, k=(lane>>4)*8+j
      a[rg] = *(const bf16x8*)&hbuf[(row * 512 + ks * 32 + q * 8) ^ ((row & 7) << 3)];
    }
    #pragma unroll
    for (int i = 0; i < 8; ++i)
      b[i] = *(const bf16x8*)(wb + (size_t)((8 * wv + i) * 16 + ks) * 512 + (size_t)l * 8);
    #pragma unroll
    for (int rg = 0; rg < 4; ++rg)
      #pragma unroll
      for (int i = 0; i < 8; ++i)
        acc[rg][i] = __builtin_amdgcn_mfma_f32_16x16x32_bf16(a[rg], b[i], acc[rg][i], 0, 0, 0);
  }
  store_h(acc, bias, hbuf, wv, q, n);
}

// ---------------------------------------------------------------------------
// z_target encoder: block = 64 rows, 256 threads (4 waves), LDS = 64KB hbuf
// only -> 2 blocks/CU. Waves partition the 32 col-tiles (8 each); weights
// come straight from L2 (1.15MB total, fits per-XCD L2).
// ---------------------------------------------------------------------------
__global__ __launch_bounds__(256, 2) void encoder_tgt(
    const float* __restrict__ xnext, const u16* __restrict__ wf,
    const float* __restrict__ b1, const float* __restrict__ b2,
    const float* __restrict__ b3, const float* __restrict__ bo_,
    float* __restrict__ ztgt) {
  __shared__ __align__(16) u16 hbuf[64 * 512];   // 64KB, swizzled
  const int tid = threadIdx.x;
  const int wv = tid >> 6, l = tid & 63;
  const int q = l >> 4, n = l & 15;
  const size_t row0 = (size_t)blockIdx.x * 64;

  // stage x -> hbuf (bf16) + exact fp32 pass-through to ztgt cols 0..31
  {
    const int r = tid >> 2, k0 = (tid & 3) * 8;
    f32x4 x0 = *(const f32x4*)(xnext + (row0 + r) * 32 + k0);
    f32x4 x1 = *(const f32x4*)(xnext + (row0 + r) * 32 + k0 + 4);
    *(f32x4*)(ztgt + (row0 + r) * 128 + k0)     = x0;
    *(f32x4*)(ztgt + (row0 + r) * 128 + k0 + 4) = x1;
    bf16x8 v;
    #pragma unroll
    for (int j = 0; j < 4; ++j) { v[j] = (short)f2bf(x0[j]); v[4 + j] = (short)f2bf(x1[j]); }
    *(bf16x8*)&hbuf[(r * 512 + k0) ^ ((r & 7) << 3)] = v;
  }
  __syncthreads();

  // ---- layer 1 (K=32, single ks-chunk) ----
  {
    f32x4 acc[4][8];
    #pragma unroll
    for (int rg = 0; rg < 4; ++rg)
      #pragma unroll
      for (int i = 0; i < 8; ++i) acc[rg][i] = (f32x4){0.f, 0.f, 0.f, 0.f};
    bf16x8 a[4];
    #pragma unroll
    for (int rg = 0; rg < 4; ++rg) {
      const int row = rg * 16 + n;
      a[rg] = *(const bf16x8*)&hbuf[(row * 512 + q * 8) ^ ((row & 7) << 3)];
    }
    #pragma unroll
    for (int i = 0; i < 8; ++i) {
      bf16x8 b = *(const bf16x8*)(wf + OFF_W1 + (size_t)(8 * wv + i) * 512 + (size_t)l * 8);
      #pragma unroll
      for (int rg = 0; rg < 4; ++rg)
        acc[rg][i] = __builtin_amdgcn_mfma_f32_16x16x32_bf16(a[rg], b, acc[rg][i], 0, 0, 0);
    }
    store_h(acc, b1, hbuf, wv, q, n);
  }

  // ---- layers 2, 3 ----
  big_layer(wf + OFF_W2, b2, hbuf, wv, l, q, n);
  big_layer(wf + OFF_W3, b3, hbuf, wv, l, q, n);

  // ---- output layer: 6 col-tiles over waves 0..2, write ztgt directly ----
  if (wv < 3) {
    f32x4 o[4][2];
    #pragma unroll
    for (int rg = 0; rg < 4; ++rg)
      #pragma unroll
      for (int i = 0; i < 2; ++i) o[rg][i] = (f32x4){0.f, 0.f, 0.f, 0.f};
    #pragma unroll 4
    for (int ks = 0; ks < 16; ++ks) {
      bf16x8 a[4];
      #pragma unroll
      for (int rg = 0; rg < 4; ++rg) {
        const int row = rg * 16 + n;
        a[rg] = *(const bf16x8*)&hbuf[(row * 512 + ks * 32 + q * 8) ^ ((row & 7) << 3)];
      }
      #pragma unroll
      for (int i = 0; i < 2; ++i) {
        bf16x8 b = *(const bf16x8*)(wf + OFF_WO + (size_t)((2 * wv + i) * 16 + ks) * 512 + (size_t)l * 8);
        #pragma unroll
        for (int rg = 0; rg < 4; ++rg)
          o[rg][i] = __builtin_amdgcn_mfma_f32_16x16x32_bf16(a[rg], b, o[rg][i], 0, 0, 0);
      }
    }
    #pragma unroll
    for (int i = 0; i < 2; ++i) {
      const float bia = bo_[(2 * wv + i) * 16 + n];
      #pragma unroll
      for (int rg = 0; rg < 4; ++rg)
        #pragma unroll
        for (int r = 0; r < 4; ++r)
          ztgt[(row0 + rg * 16 + q * 4 + r) * 128 + 32 + (2 * wv + i) * 16 + n] = o[rg][i][r] + bia;
    }
  }
}

// ---------------------------------------------------------------------------
// z_k encoder — exact fp32 VALU (unchanged from R3).
// ---------------------------------------------------------------------------
__global__ __launch_bounds__(256) void encoder_zk_f32(
    const float* __restrict__ xk,
    const float* __restrict__ W1, const float* __restrict__ b1,
    const float* __restrict__ W2, const float* __restrict__ b2,
    const float* __restrict__ W3, const float* __restrict__ b3,
    const float* __restrict__ Wo, const float* __restrict__ bo_,
    float* __restrict__ zk_out) {
  __shared__ __align__(16) float hb[2][8][512];
  __shared__ __align__(16) float xb[8][32];
  const int t = threadIdx.x;
  const int row0 = blockIdx.x * 8;
  {
    int r = t >> 5, j = t & 31;
    float v = xk[(size_t)(row0 + r) * 32 + j];
    xb[r][j] = v;
    zk_out[(size_t)(row0 + r) * 128 + j] = v;      // x pass-through
  }
  __syncthreads();
  const int c0 = t, c1 = t + 256;
  // layer 1: K=32, xb -> hb[0]
  {
    float a0[8], a1[8];
    const float i0 = b1[c0], i1 = b1[c1];
    #pragma unroll
    for (int r = 0; r < 8; ++r) { a0[r] = i0; a1[r] = i1; }
    for (int k = 0; k < 32; k += 4) {
      float w00 = W1[(size_t)(k+0)*512 + c0], w10 = W1[(size_t)(k+0)*512 + c1];
      float w01 = W1[(size_t)(k+1)*512 + c0], w11 = W1[(size_t)(k+1)*512 + c1];
      float w02 = W1[(size_t)(k+2)*512 + c0], w12 = W1[(size_t)(k+2)*512 + c1];
      float w03 = W1[(size_t)(k+3)*512 + c0], w13 = W1[(size_t)(k+3)*512 + c1];
      #pragma unroll
      for (int r = 0; r < 8; ++r) {
        f32x4 z = *(const f32x4*)&xb[r][k];
        a0[r] += z[0]*w00 + z[1]*w01 + z[2]*w02 + z[3]*w03;
        a1[r] += z[0]*w10 + z[1]*w11 + z[2]*w12 + z[3]*w13;
      }
    }
    #pragma unroll
    for (int r = 0; r < 8; ++r) { hb[0][r][c0] = fmaxf(a0[r], 0.f); hb[0][r][c1] = fmaxf(a1[r], 0.f); }
  }
  __syncthreads();
  // layers 2,3: K=512
  #pragma unroll
  for (int lyr = 0; lyr < 2; ++lyr) {
    const float* W = lyr ? W3 : W2;
    const float* bb = lyr ? b3 : b2;
    const float (*hin)[512] = hb[lyr & 1];
    float (*hout)[512] = hb[(lyr & 1) ^ 1];
    float a0[8], a1[8];
    const float i0 = bb[c0], i1 = bb[c1];
    #pragma unroll
    for (int r = 0; r < 8; ++r) { a0[r] = i0; a1[r] = i1; }
    for (int k = 0; k < 512; k += 4) {
      float w00 = W[(size_t)(k+0)*512 + c0], w10 = W[(size_t)(k+0)*512 + c1];
      float w01 = W[(size_t)(k+1)*512 + c0], w11 = W[(size_t)(k+1)*512 + c1];
      float w02 = W[(size_t)(k+2)*512 + c0], w12 = W[(size_t)(k+2)*512 + c1];
      float w03 = W[(size_t)(k+3)*512 + c0], w13 = W[(size_t)(k+3)*512 + c1];
      #pragma unroll
      for (int r = 0; r < 8; ++r) {
        f32x4 z = *(const f32x4*)&hin[r][k];
        a0[r] += z[0]*w00 + z[1]*w01 + z[2]*w02 + z[3]*w03;
        a1[r] += z[0]*w10 + z[1]*w11 + z[2]*w12 + z[3]*w13;
      }
    }
    #pragma unroll
    for (int r = 0; r < 8; ++r) { hout[r][c0] = fmaxf(a0[r], 0.f); hout[r][c1] = fmaxf(a1[r], 0.f); }
    __syncthreads();
  }
  // output layer: N=96
  if (t < 96) {
    float a[8];
    const float i0 = bo_[t];
    #pragma unroll
    for (int r = 0; r < 8; ++r) a[r] = i0;
    for (int k = 0; k < 512; k += 4) {
      float w0 = Wo[(size_t)(k+0)*96 + t];
      float w1 = Wo[(size_t)(k+1)*96 + t];
      float w2 = Wo[(size_t)(k+2)*96 + t];
      float w3 = Wo[(size_t)(k+3)*96 + t];
      #pragma unroll
      for (int r = 0; r < 8; ++r) {
        f32x4 z = *(const f32x4*)&hb[0][r][k];
        a[r] += z[0]*w0 + z[1]*w1 + z[2]*w2 + z[3]*w3;
      }
    }
    #pragma unroll
    for (int r = 0; r < 8; ++r)
      zk_out[(size_t)(row0 + r) * 128 + 32 + t] = a[r];
  }
}

// ---------------------------------------------------------------------------
// Scan: z_{s+1} = z_s @ A + u[:,s,:] @ Bmat, 64 steps, all fp32.
// R4: block = 4 rows, 256 threads = 128 cols x 2 row-groups (2 rows/thread).
// Thread's A column (128 f32) lives in VGPRs for all 64 steps; u pre-staged
// in LDS; z round-trips through 4KB ping-pong LDS (broadcast reads).
// f32x4 partial sums -> 8 parallel FMA chains instead of one serial chain.
// ---------------------------------------------------------------------------
__global__ __launch_bounds__(256, 2) void scan_kernel(
    const float* __restrict__ zk, const float* __restrict__ Af,
    const float* __restrict__ Bm, const float* __restrict__ useq,
    float* __restrict__ zpred, float* __restrict__ xpred) {
  __shared__ __align__(16) float ubuf[4 * 512];    // 4 rows x 64 steps x 8
  __shared__ __align__(16) float zbuf[2][4 * 128];
  const int t = threadIdx.x;
  const int b0 = blockIdx.x * 4;
  const int c = t & 127, g = t >> 7;

  // stage u (coalesced, contiguous per block) and z0
  *(f32x4*)&ubuf[t * 4]        = *(const f32x4*)(useq + (size_t)b0 * 512 + t * 4);
  *(f32x4*)&ubuf[1024 + t * 4] = *(const f32x4*)(useq + (size_t)b0 * 512 + 1024 + t * 4);
  if (t < 128) *(f32x4*)&zbuf[0][t * 4] = *(const f32x4*)(zk + (size_t)b0 * 128 + t * 4);

  // A column c -> registers (loop-invariant across all 64 steps)
  f32x4 ar[32];
  #pragma unroll
  for (int kk = 0; kk < 32; ++kk) {
    ar[kk][0] = Af[(size_t)(4 * kk + 0) * 128 + c];
    ar[kk][1] = Af[(size_t)(4 * kk + 1) * 128 + c];
    ar[kk][2] = Af[(size_t)(4 * kk + 2) * 128 + c];
    ar[kk][3] = Af[(size_t)(4 * kk + 3) * 128 + c];
  }
  float bm[8];
  #pragma unroll
  for (int j = 0; j < 8; ++j) bm[j] = Bm[j * 128 + c];
  __syncthreads();

  const int r0 = 2 * g, r1 = 2 * g + 1;
  const size_t o0 = (size_t)(b0 + r0) * 64;
  const size_t o1 = (size_t)(b0 + r1) * 64;
  int cur = 0;
  #pragma unroll 1
  for (int s = 0; s < 64; ++s) {
    f32x4 ua0 = *(const f32x4*)&ubuf[r0 * 512 + s * 8];
    f32x4 ub0 = *(const f32x4*)&ubuf[r0 * 512 + s * 8 + 4];
    f32x4 ua1 = *(const f32x4*)&ubuf[r1 * 512 + s * 8];
    f32x4 ub1 = *(const f32x4*)&ubuf[r1 * 512 + s * 8 + 4];
    f32x4 v0, v1;
    #pragma unroll
    for (int j = 0; j < 4; ++j) {
      v0[j] = ua0[j] * bm[j] + ub0[j] * bm[4 + j];
      v1[j] = ua1[j] * bm[j] + ub1[j] * bm[4 + j];
    }
    const float* z0p = &zbuf[cur][r0 * 128];
    const float* z1p = &zbuf[cur][r1 * 128];
    #pragma unroll
    for (int kk = 0; kk < 32; ++kk) {
      f32x4 a  = ar[kk];
      f32x4 za = *(const f32x4*)&z0p[kk * 4];
      f32x4 zb = *(const f32x4*)&z1p[kk * 4];
      v0 += za * a;
      v1 += zb * a;
    }
    const float acc0 = (v0[0] + v0[1]) + (v0[2] + v0[3]);
    const float acc1 = (v1[0] + v1[1]) + (v1[2] + v1[3]);
    zbuf[cur ^ 1][r0 * 128 + c] = acc0;
    zbuf[cur ^ 1][r1 * 128 + c] = acc1;
    zpred[(o0 + s) * 128 + c] = acc0;
    zpred[(o1 + s) * 128 + c] = acc1;
    if (c < 32) {
      xpred[(o0 + s) * 32 + c] = acc0;
      xpred[(o1 + s) * 32 + c] = acc1;
    }
    __syncthreads();
    cur ^= 1;
  }
}

// ---------------------------------------------------------------------------
extern "C" void kernel_launch(void* const* d_in, const int* in_sizes, int n_in,
                              void* d_out, int out_size, void* d_ws, size_t ws_size,
                              hipStream_t stream) {
  (void)in_sizes; (void)n_in; (void)out_size; (void)ws_size;
  const float* xk    = (const float*)d_in[0];
  const float* useq  = (const float*)d_in[1];
  const float* xnext = (const float*)d_in[2];
  const float* W1 = (const float*)d_in[3];
  const float* b1 = (const float*)d_in[4];
  const float* W2 = (const float*)d_in[5];
  const float* b2 = (const float*)d_in[6];
  const float* W3 = (const float*)d_in[7];
  const float* b3 = (const float*)d_in[8];
  const float* Wo = (const float*)d_in[9];
  const float* bo = (const float*)d_in[10];
  const float* A  = (const float*)d_in[11];
  const float* Bm = (const float*)d_in[12];

  float* out   = (float*)d_out;
  float* zpred = out;
  float* xpred = out + XPRED_OFF;
  float* ztgt  = out + ZTGT_OFF;
  u16*   wf    = (u16*)d_ws;
  float* zkw   = (float*)((char*)d_ws + OFF_ZK_BYTES);

  prep_swizzle<<<1152, 64, 0, stream>>>(W1, W2, W3, Wo, wf);
  encoder_zk_f32<<<256, 256, 0, stream>>>(xk, W1, b1, W2, b2, W3, b3, Wo, bo, zkw);
  scan_kernel<<<512, 256, 0, stream>>>(zkw, A, Bm, useq, zpred, xpred);
  encoder_tgt<<<2048, 256, 0, stream>>>(xnext, wf, b1, b2, b3, bo, ztgt);
}

// Round 2
// 528.689 us; speedup vs baseline: 1.4686x; 1.4686x over previous
//
#include <hip/hip_runtime.h>

// DeepKoopmanNoDec — fp32 in/out. R5: R4's h-in-LDS + global->VGPR weight
// streaming was right structurally but spilled ~512B/thread (WRITE_SIZE
// 65->326MB = scratch): acc[4][8]+b[8] needed ~200 VGPR, compiler capped at
// 128 and spilled. R5 halves the per-wave tile: 8 waves x (64 rows x 64
// cols), acc[4][4]=64 VGPR, a[4]+b[4]=32 -> ~120 live, no spill. Same 4x
// MFMA reuse on both operands, B-frags still read once per block from L2.
// Shapes: B=2048, M=64, STATE=32, EMBED=96, LATENT=128, HIDDEN=512.

typedef unsigned short u16;
typedef __attribute__((ext_vector_type(8))) short bf16x8;   // MFMA A/B frag (4 VGPRs)
typedef __attribute__((ext_vector_type(4))) short bf16x4;   // 8B packed store
typedef __attribute__((ext_vector_type(4))) float f32x4;    // MFMA C/D frag

// ws layout: bf16 B-frag weights, then fp32 z_k
#define OFF_W1 0              // 32 frags   (K=32 , N=512)
#define OFF_W2 16384          // 512 frags  (K=512, N=512)
#define OFF_W3 278528         // 512 frags
#define OFF_WO 540672         // 96 frags   (K=512, N=96)
#define OFF_ZK_BYTES 1179648  // fp32 z_k: 2048*128 floats

// d_out regions (float elements): z_pred | x_pred | z_target
#define XPRED_OFF 16777216
#define ZTGT_OFF  20971520

__device__ __forceinline__ float bf2f(u16 u) {
  unsigned int i = ((unsigned int)u) << 16;
  return __builtin_bit_cast(float, i);
}
__device__ __forceinline__ u16 f2bf(float f) {   // round-to-nearest-even
  unsigned int i = __builtin_bit_cast(unsigned int, f);
  i = (i + 0x7FFFu + ((i >> 16) & 1u)) >> 16;
  return (u16)i;
}

// ---------------------------------------------------------------------------
// Prep: swizzle fp32 weights (row-major K x N) into bf16 B-fragment-linear
// layout. frag f = ct*(K/32)+ks; lane l holds W[ks*32+(l>>4)*8+j][ct*16+(l&15)]
// at u16 offset f*512 + l*8 -> one dwordx4 per lane. (unchanged)
// ---------------------------------------------------------------------------
__global__ void prep_swizzle(const float* __restrict__ W1, const float* __restrict__ W2,
                             const float* __restrict__ W3, const float* __restrict__ Wo,
                             u16* __restrict__ dst) {
  int f = blockIdx.x;
  int l = threadIdx.x;
  const float* src; int K, N; u16* d;
  if (f < 32)        { src = W1; K = 32;  N = 512; d = dst + OFF_W1; }
  else if (f < 544)  { src = W2; K = 512; N = 512; d = dst + OFF_W2; f -= 32; }
  else if (f < 1056) { src = W3; K = 512; N = 512; d = dst + OFF_W3; f -= 544; }
  else               { src = Wo; K = 512; N = 96;  d = dst + OFF_WO; f -= 1056; }
  const int KF = K >> 5;
  const int ct = f / KF, ks = f - ct * KF;
  const int q = l >> 4, n = l & 15;
  const int kbase = ks * 32 + q * 8;
  const int col = ct * 16 + n;
  bf16x8 vh;
  #pragma unroll
  for (int j = 0; j < 8; ++j)
    vh[j] = (short)f2bf(src[(size_t)(kbase + j) * N + col]);
  *(bf16x8*)(d + ((size_t)f * 64 + l) * 8) = vh;
}

// ---------------------------------------------------------------------------
// encoder_tgt. hbuf: row-major [64][512] bf16, XOR swizzle on u16 index:
// idx = (row*512 + k) ^ ((row&7)<<3). XOR sits in idx bits 3-5 -> any
// <=16B access aligned to 8 u16 stays contiguous; A-frag reads (16 lanes
// at row stride 1024B, same-bank unswizzled) spread over 8 bank-quads ->
// 8 lanes/quad = exactly the b128 minimum, conflict-free schedule.
// ---------------------------------------------------------------------------
__device__ __forceinline__ void store_h(const f32x4 (&acc)[4][4],
                                        const float* __restrict__ bias,
                                        u16* hbuf, int wv, int q, int n) {
  __syncthreads();                       // all readers of previous h done
  #pragma unroll
  for (int i = 0; i < 4; ++i) {
    const int col = wv * 64 + i * 16 + n;
    const float bia = bias[col];
    #pragma unroll
    for (int rg = 0; rg < 4; ++rg) {
      #pragma unroll
      for (int r = 0; r < 4; ++r) {
        const int row = rg * 16 + q * 4 + r;    // C layout: col=lane&15, row=(lane>>4)*4+r
        hbuf[(row * 512 + col) ^ ((row & 7) << 3)] = f2bf(fmaxf(acc[rg][i][r] + bia, 0.f));
      }
    }
  }
  __syncthreads();                       // new h visible to all waves
}

// One HIDDEN->HIDDEN layer: wave wv owns coltiles wv*4..wv*4+3 (64 cols) x
// all 64 rows. Per ks: 4 LDS A-frags + 4 L2 B-frags feed 16 MFMAs (4x reuse
// both sides). No barriers inside the K loop.
__device__ __forceinline__ void big_layer(const u16* __restrict__ wb,
                                          const float* __restrict__ bias,
                                          u16* hbuf, int wv, int l, int q, int n) {
  f32x4 acc[4][4];
  #pragma unroll
  for (int rg = 0; rg < 4; ++rg)
    #pragma unroll
    for (int i = 0; i < 4; ++i) acc[rg][i] = (f32x4){0.f, 0.f, 0.f, 0.f};
  #pragma unroll 2
  for (int ks = 0; ks < 16; ++ks) {
    bf16x8 b[4], a[4];
    #pragma unroll
    for (int i = 0; i < 4; ++i)
      b[i] = *(const bf16x8*)(wb + (size_t)((4 * wv + i) * 16 + ks) * 512 + (size_t)l * 8);
    #pragma unroll
    for (int rg = 0; rg < 4; ++rg) {
      const int row = rg * 16 + n;       // A layout: row=lane&15, k=(lane>>4)*8+j
      a[rg] = *(const bf16x8*)&hbuf[(row * 512 + ks * 32 + q * 8) ^ ((row & 7) << 3)];
    }
    #pragma unroll
    for (int rg = 0; rg < 4; ++rg)
      #pragma unroll
      for (int i = 0; i < 4; ++i)
        acc[rg][i] = __builtin_amdgcn_mfma_f32_16x16x32_bf16(a[rg], b[i], acc[rg][i], 0, 0, 0);
  }
  store_h(acc, bias, hbuf, wv, q, n);
}

// ---------------------------------------------------------------------------
// z_target encoder: block = 64 rows, 512 threads (8 waves), LDS = 64KB hbuf.
// Waves partition the 32 col-tiles (4 each); weights straight from L2
// (1.15MB total, fits per-XCD L2).
// ---------------------------------------------------------------------------
__global__ __launch_bounds__(512, 2) void encoder_tgt(
    const float* __restrict__ xnext, const u16* __restrict__ wf,
    const float* __restrict__ b1, const float* __restrict__ b2,
    const float* __restrict__ b3, const float* __restrict__ bo_,
    float* __restrict__ ztgt) {
  __shared__ __align__(16) u16 hbuf[64 * 512];   // 64KB, swizzled
  const int tid = threadIdx.x;
  const int wv = tid >> 6, l = tid & 63;
  const int q = l >> 4, n = l & 15;
  const size_t row0 = (size_t)blockIdx.x * 64;

  // stage x -> hbuf (bf16) + exact fp32 pass-through to ztgt cols 0..31
  {
    const int r = tid >> 3, k0 = (tid & 7) * 4;
    f32x4 x = *(const f32x4*)(xnext + (row0 + r) * 32 + k0);
    *(f32x4*)(ztgt + (row0 + r) * 128 + k0) = x;
    bf16x4 v;
    #pragma unroll
    for (int j = 0; j < 4; ++j) v[j] = (short)f2bf(x[j]);
    *(bf16x4*)&hbuf[(r * 512 + k0) ^ ((r & 7) << 3)] = v;
  }
  __syncthreads();

  // ---- layer 1 (K=32, single ks-chunk) ----
  {
    f32x4 acc[4][4];
    #pragma unroll
    for (int rg = 0; rg < 4; ++rg)
      #pragma unroll
      for (int i = 0; i < 4; ++i) acc[rg][i] = (f32x4){0.f, 0.f, 0.f, 0.f};
    bf16x8 a[4];
    #pragma unroll
    for (int rg = 0; rg < 4; ++rg) {
      const int row = rg * 16 + n;
      a[rg] = *(const bf16x8*)&hbuf[(row * 512 + q * 8) ^ ((row & 7) << 3)];
    }
    #pragma unroll
    for (int i = 0; i < 4; ++i) {
      bf16x8 b = *(const bf16x8*)(wf + OFF_W1 + (size_t)(4 * wv + i) * 512 + (size_t)l * 8);
      #pragma unroll
      for (int rg = 0; rg < 4; ++rg)
        acc[rg][i] = __builtin_amdgcn_mfma_f32_16x16x32_bf16(a[rg], b, acc[rg][i], 0, 0, 0);
    }
    store_h(acc, b1, hbuf, wv, q, n);
  }

  // ---- layers 2, 3 ----
  big_layer(wf + OFF_W2, b2, hbuf, wv, l, q, n);
  big_layer(wf + OFF_W3, b3, hbuf, wv, l, q, n);

  // ---- output layer: 6 col-tiles, waves 0..5 one tile each ----
  if (wv < 6) {
    f32x4 o[4];
    #pragma unroll
    for (int rg = 0; rg < 4; ++rg) o[rg] = (f32x4){0.f, 0.f, 0.f, 0.f};
    #pragma unroll 2
    for (int ks = 0; ks < 16; ++ks) {
      bf16x8 b = *(const bf16x8*)(wf + OFF_WO + (size_t)(wv * 16 + ks) * 512 + (size_t)l * 8);
      #pragma unroll
      for (int rg = 0; rg < 4; ++rg) {
        const int row = rg * 16 + n;
        bf16x8 a = *(const bf16x8*)&hbuf[(row * 512 + ks * 32 + q * 8) ^ ((row & 7) << 3)];
        o[rg] = __builtin_amdgcn_mfma_f32_16x16x32_bf16(a, b, o[rg], 0, 0, 0);
      }
    }
    const float bia = bo_[wv * 16 + n];
    #pragma unroll
    for (int rg = 0; rg < 4; ++rg)
      #pragma unroll
      for (int r = 0; r < 4; ++r)
        ztgt[(row0 + rg * 16 + q * 4 + r) * 128 + 32 + wv * 16 + n] = o[rg][r] + bia;
  }
}

// ---------------------------------------------------------------------------
// z_k encoder — exact fp32 VALU (unchanged).
// ---------------------------------------------------------------------------
__global__ __launch_bounds__(256) void encoder_zk_f32(
    const float* __restrict__ xk,
    const float* __restrict__ W1, const float* __restrict__ b1,
    const float* __restrict__ W2, const float* __restrict__ b2,
    const float* __restrict__ W3, const float* __restrict__ b3,
    const float* __restrict__ Wo, const float* __restrict__ bo_,
    float* __restrict__ zk_out) {
  __shared__ __align__(16) float hb[2][8][512];
  __shared__ __align__(16) float xb[8][32];
  const int t = threadIdx.x;
  const int row0 = blockIdx.x * 8;
  {
    int r = t >> 5, j = t & 31;
    float v = xk[(size_t)(row0 + r) * 32 + j];
    xb[r][j] = v;
    zk_out[(size_t)(row0 + r) * 128 + j] = v;      // x pass-through
  }
  __syncthreads();
  const int c0 = t, c1 = t + 256;
  // layer 1: K=32, xb -> hb[0]
  {
    float a0[8], a1[8];
    const float i0 = b1[c0], i1 = b1[c1];
    #pragma unroll
    for (int r = 0; r < 8; ++r) { a0[r] = i0; a1[r] = i1; }
    for (int k = 0; k < 32; k += 4) {
      float w00 = W1[(size_t)(k+0)*512 + c0], w10 = W1[(size_t)(k+0)*512 + c1];
      float w01 = W1[(size_t)(k+1)*512 + c0], w11 = W1[(size_t)(k+1)*512 + c1];
      float w02 = W1[(size_t)(k+2)*512 + c0], w12 = W1[(size_t)(k+2)*512 + c1];
      float w03 = W1[(size_t)(k+3)*512 + c0], w13 = W1[(size_t)(k+3)*512 + c1];
      #pragma unroll
      for (int r = 0; r < 8; ++r) {
        f32x4 z = *(const f32x4*)&xb[r][k];
        a0[r] += z[0]*w00 + z[1]*w01 + z[2]*w02 + z[3]*w03;
        a1[r] += z[0]*w10 + z[1]*w11 + z[2]*w12 + z[3]*w13;
      }
    }
    #pragma unroll
    for (int r = 0; r < 8; ++r) { hb[0][r][c0] = fmaxf(a0[r], 0.f); hb[0][r][c1] = fmaxf(a1[r], 0.f); }
  }
  __syncthreads();
  // layers 2,3: K=512
  #pragma unroll
  for (int lyr = 0; lyr < 2; ++lyr) {
    const float* W = lyr ? W3 : W2;
    const float* bb = lyr ? b3 : b2;
    const float (*hin)[512] = hb[lyr & 1];
    float (*hout)[512] = hb[(lyr & 1) ^ 1];
    float a0[8], a1[8];
    const float i0 = bb[c0], i1 = bb[c1];
    #pragma unroll
    for (int r = 0; r < 8; ++r) { a0[r] = i0; a1[r] = i1; }
    for (int k = 0; k < 512; k += 4) {
      float w00 = W[(size_t)(k+0)*512 + c0], w10 = W[(size_t)(k+0)*512 + c1];
      float w01 = W[(size_t)(k+1)*512 + c0], w11 = W[(size_t)(k+1)*512 + c1];
      float w02 = W[(size_t)(k+2)*512 + c0], w12 = W[(size_t)(k+2)*512 + c1];
      float w03 = W[(size_t)(k+3)*512 + c0], w13 = W[(size_t)(k+3)*512 + c1];
      #pragma unroll
      for (int r = 0; r < 8; ++r) {
        f32x4 z = *(const f32x4*)&hin[r][k];
        a0[r] += z[0]*w00 + z[1]*w01 + z[2]*w02 + z[3]*w03;
        a1[r] += z[0]*w10 + z[1]*w11 + z[2]*w12 + z[3]*w13;
      }
    }
    #pragma unroll
    for (int r = 0; r < 8; ++r) { hout[r][c0] = fmaxf(a0[r], 0.f); hout[r][c1] = fmaxf(a1[r], 0.f); }
    __syncthreads();
  }
  // output layer: N=96
  if (t < 96) {
    float a[8];
    const float i0 = bo_[t];
    #pragma unroll
    for (int r = 0; r < 8; ++r) a[r] = i0;
    for (int k = 0; k < 512; k += 4) {
      float w0 = Wo[(size_t)(k+0)*96 + t];
      float w1 = Wo[(size_t)(k+1)*96 + t];
      float w2 = Wo[(size_t)(k+2)*96 + t];
      float w3 = Wo[(size_t)(k+3)*96 + t];
      #pragma unroll
      for (int r = 0; r < 8; ++r) {
        f32x4 z = *(const f32x4*)&hb[0][r][k];
        a[r] += z[0]*w0 + z[1]*w1 + z[2]*w2 + z[3]*w3;
      }
    }
    #pragma unroll
    for (int r = 0; r < 8; ++r)
      zk_out[(size_t)(row0 + r) * 128 + 32 + t] = a[r];
  }
}

// ---------------------------------------------------------------------------
// Scan: z_{s+1} = z_s @ A + u[:,s,:] @ Bmat, 64 steps, all fp32 (unchanged
// from R4: A column in 128 VGPRs, u in LDS, f32x4 partial accumulators).
// ---------------------------------------------------------------------------
__global__ __launch_bounds__(256, 2) void scan_kernel(
    const float* __restrict__ zk, const float* __restrict__ Af,
    const float* __restrict__ Bm, const float* __restrict__ useq,
    float* __restrict__ zpred, float* __restrict__ xpred) {
  __shared__ __align__(16) float ubuf[4 * 512];    // 4 rows x 64 steps x 8
  __shared__ __align__(16) float zbuf[2][4 * 128];
  const int t = threadIdx.x;
  const int b0 = blockIdx.x * 4;
  const int c = t & 127, g = t >> 7;

  // stage u (coalesced, contiguous per block) and z0
  *(f32x4*)&ubuf[t * 4]        = *(const f32x4*)(useq + (size_t)b0 * 512 + t * 4);
  *(f32x4*)&ubuf[1024 + t * 4] = *(const f32x4*)(useq + (size_t)b0 * 512 + 1024 + t * 4);
  if (t < 128) *(f32x4*)&zbuf[0][t * 4] = *(const f32x4*)(zk + (size_t)b0 * 128 + t * 4);

  // A column c -> registers (loop-invariant across all 64 steps)
  f32x4 ar[32];
  #pragma unroll
  for (int kk = 0; kk < 32; ++kk) {
    ar[kk][0] = Af[(size_t)(4 * kk + 0) * 128 + c];
    ar[kk][1] = Af[(size_t)(4 * kk + 1) * 128 + c];
    ar[kk][2] = Af[(size_t)(4 * kk + 2) * 128 + c];
    ar[kk][3] = Af[(size_t)(4 * kk + 3) * 128 + c];
  }
  float bm[8];
  #pragma unroll
  for (int j = 0; j < 8; ++j) bm[j] = Bm[j * 128 + c];
  __syncthreads();

  const int r0 = 2 * g, r1 = 2 * g + 1;
  const size_t o0 = (size_t)(b0 + r0) * 64;
  const size_t o1 = (size_t)(b0 + r1) * 64;
  int cur = 0;
  #pragma unroll 1
  for (int s = 0; s < 64; ++s) {
    f32x4 ua0 = *(const f32x4*)&ubuf[r0 * 512 + s * 8];
    f32x4 ub0 = *(const f32x4*)&ubuf[r0 * 512 + s * 8 + 4];
    f32x4 ua1 = *(const f32x4*)&ubuf[r1 * 512 + s * 8];
    f32x4 ub1 = *(const f32x4*)&ubuf[r1 * 512 + s * 8 + 4];
    f32x4 v0, v1;
    #pragma unroll
    for (int j = 0; j < 4; ++j) {
      v0[j] = ua0[j] * bm[j] + ub0[j] * bm[4 + j];
      v1[j] = ua1[j] * bm[j] + ub1[j] * bm[4 + j];
    }
    const float* z0p = &zbuf[cur][r0 * 128];
    const float* z1p = &zbuf[cur][r1 * 128];
    #pragma unroll
    for (int kk = 0; kk < 32; ++kk) {
      f32x4 a  = ar[kk];
      f32x4 za = *(const f32x4*)&z0p[kk * 4];
      f32x4 zb = *(const f32x4*)&z1p[kk * 4];
      v0 += za * a;
      v1 += zb * a;
    }
    const float acc0 = (v0[0] + v0[1]) + (v0[2] + v0[3]);
    const float acc1 = (v1[0] + v1[1]) + (v1[2] + v1[3]);
    zbuf[cur ^ 1][r0 * 128 + c] = acc0;
    zbuf[cur ^ 1][r1 * 128 + c] = acc1;
    zpred[(o0 + s) * 128 + c] = acc0;
    zpred[(o1 + s) * 128 + c] = acc1;
    if (c < 32) {
      xpred[(o0 + s) * 32 + c] = acc0;
      xpred[(o1 + s) * 32 + c] = acc1;
    }
    __syncthreads();
    cur ^= 1;
  }
}

// ---------------------------------------------------------------------------
extern "C" void kernel_launch(void* const* d_in, const int* in_sizes, int n_in,
                              void* d_out, int out_size, void* d_ws, size_t ws_size,
                              hipStream_t stream) {
  (void)in_sizes; (void)n_in; (void)out_size; (void)ws_size;
  const float* xk    = (const float*)d_in[0];
  const float* useq  = (const float*)d_in[1];
  const float* xnext = (const float*)d_in[2];
  const float* W1 = (const float*)d_in[3];
  const float* b1 = (const float*)d_in[4];
  const float* W2 = (const float*)d_in[5];
  const float* b2 = (const float*)d_in[6];
  const float* W3 = (const float*)d_in[7];
  const float* b3 = (const float*)d_in[8];
  const float* Wo = (const float*)d_in[9];
  const float* bo = (const float*)d_in[10];
  const float* A  = (const float*)d_in[11];
  const float* Bm = (const float*)d_in[12];

  float* out   = (float*)d_out;
  float* zpred = out;
  float* xpred = out + XPRED_OFF;
  float* ztgt  = out + ZTGT_OFF;
  u16*   wf    = (u16*)d_ws;
  float* zkw   = (float*)((char*)d_ws + OFF_ZK_BYTES);

  prep_swizzle<<<1152, 64, 0, stream>>>(W1, W2, W3, Wo, wf);
  encoder_zk_f32<<<256, 256, 0, stream>>>(xk, W1, b1, W2, b2, W3, b3, Wo, bo, zkw);
  scan_kernel<<<512, 256, 0, stream>>>(zkw, A, Bm, useq, zpred, xpred);
  encoder_tgt<<<2048, 512, 0, stream>>>(xnext, wf, b1, b2, b3, bo, ztgt);
}